// Round 17
// baseline (66.974 us; speedup 1.0000x reference)
//
#include <hip/hip_runtime.h>

#define T_WPAD  962048   // reflect-padded waveform length (before zero tail)
#define T_RAW   960000
#define NFRM    1879
#define OUTW    1876
#define MEDLEN  1864
#define WINL    30
#define PADL    14
#define FPB     4        // frames per block
#define NBX     470      // ceil(NFRM / FPB)
#define XLEN    2244     // 3*512 + 705 + pad (float4-divisible)
#define X4LEN   561

// Rotated inner body: window offset O (0/4/8/12), all indices compile-time.
// Reads w[(O+1)..(O+15) mod 16]; loads content k+4 into the retiring slots
// w[O..O+3]; loads A(k+1). PA/PW select the source (global or LDS base).
// 2 loads + 48 fmaf, nothing else.
#define NCCF_BODY(O, AUSE, ALOAD, K, PA, PW)                                    \
    {                                                                           \
        ALOAD = PA[(K) + 1];                                                    \
        float4 nx = PW[(K) + 4];                                                \
        _Pragma("unroll")                                                       \
        for (int r = 0; r < 12; ++r) {                                          \
            acc[r] = fmaf(AUSE.x, w[(O + r + 1) & 15], acc[r]);                 \
            acc[r] = fmaf(AUSE.y, w[(O + r + 2) & 15], acc[r]);                 \
            acc[r] = fmaf(AUSE.z, w[(O + r + 3) & 15], acc[r]);                 \
            acc[r] = fmaf(AUSE.w, w[(O + r + 4) & 15], acc[r]);                 \
        }                                                                       \
        w[(O + 0) & 15] = nx.x; w[(O + 1) & 15] = nx.y;                         \
        w[(O + 2) & 15] = nx.z; w[(O + 3) & 15] = nx.w;                         \
    }

// Prologue + main loop over a given pair of base pointers.
#define NCCF_RUN(PA, PW)                                                        \
    {                                                                           \
        const float4* fb = (PA) + 8 * s;                                        \
        _Pragma("unroll")                                                       \
        for (int m = 0; m < 8; ++m) {                                           \
            float4 v4 = fb[m];                                                  \
            T0 += (double)v4.x * v4.x; T0 += (double)v4.y * v4.y;               \
            T0 += (double)v4.z * v4.z; T0 += (double)v4.w * v4.w;               \
        }                                                                       \
        _Pragma("unroll")                                                       \
        for (int off = 8; off >= 1; off >>= 1) T0 += __shfl_xor(T0, off, 16);   \
        _Pragma("unroll")                                                       \
        for (int d = 0; d < 4; ++d) {                                           \
            float4 t4 = (PW)[d];                                                \
            w[4*d] = t4.x; w[4*d+1] = t4.y; w[4*d+2] = t4.z; w[4*d+3] = t4.w;   \
        }                                                                       \
        _Pragma("unroll")                                                       \
        for (int j = 0; j < 12; ++j) sq[j] = w[j] * w[j];                       \
        Aev = (PA)[0];                                                          \
        _Pragma("unroll 2")                                                     \
        for (int kg = 0; kg < 32; ++kg) {                                       \
            const int k4 = kg * 4;                                              \
            NCCF_BODY(0,  Aev, Aod, k4 + 0, (PA), (PW))                         \
            NCCF_BODY(4,  Aod, Aev, k4 + 1, (PA), (PW))                         \
            NCCF_BODY(8,  Aev, Aod, k4 + 2, (PA), (PW))                         \
            NCCF_BODY(12, Aod, Aev, k4 + 3, (PA), (PW))                         \
        }                                                                       \
    }

// ---------------- Kernel 1: NCCF + per-frame lag selection ----------------
// 64 thr = 1 wave per block; wave handles FOUR frames (one per 16-lane group).
// g = lane>>4 picks frame, s = lane&15 owns lags 12s+1..12s+12.
// INTERIOR blocks (bx 1..468): no staging, no barrier, no LDS at all —
// A-stream and window stream read straight from global (L1/L2-resident,
// float4-aligned, imm-offset addressable). VMEM pipe was idle; LDS pipe
// demand -> 0. BOUNDARY blocks (16 total): R16 staged-LDS path verbatim.
// Norms: cooperative f64 frame norm T0 + neighbor-recurrence shuffle scan.
__global__ __launch_bounds__(64) void nccf_kernel(const float* __restrict__ wav,
                                                  int* __restrict__ idxArr) {
    const int bx   = blockIdx.x;
    const int b    = blockIdx.y;
    const int tid  = threadIdx.x;
    const int lane = tid & 63;
    const int g    = lane >> 4;          // frame within block (0..3)
    const int s    = lane & 15;          // lag-group lane (0..15)

    __shared__ __align__(16) float X[XLEN];   // used only by boundary blocks

    const long a0 = (long)bx * (FPB * 512);
    const float* wrow = wav + (long)b * T_RAW;
    const bool interior = (bx >= 1 && bx <= NBX - 2);

    if (!interior) {
        for (int i = tid; i < XLEN; i += 64) {
            float v = 0.0f;
            long t = a0 + i;
            if (t < T_WPAD) {
                long u = t - 1024;
                if (u < 0) u = -u;
                if (u >= T_RAW) u = 2L * (T_RAW - 1) - u;
                v = wrow[u];
            }
            X[i] = v;
        }
        __syncthreads();
    }

    const int F  = g;                    // frame within block
    const int gf = bx * FPB + F;         // global frame
    const bool valid = (gf < NFRM);

    double T0 = 0.0;
    float acc[12];
    #pragma unroll
    for (int r = 0; r < 12; ++r) acc[r] = 0.0f;
    float sq[12];                        // X[12s+j]^2, j=0..11
    float w[16];
    float4 Aev, Aod;

    if (interior) {
        // wp[a0 + e] == wav[b*T_RAW + a0 - 1024 + e] for all tile elements.
        const float4* G4 = (const float4*)(wrow + (a0 - 1024));
        const float4* pA = G4 + F * 128;      // frame base (float4)
        const float4* pW = pA + 3 * s;        // lane window base (float4)
        NCCF_RUN(pA, pW)
    } else {
        const float4* X4 = (const float4*)X;
        const float4* pA = X4 + F * 128;
        const float4* pW = pA + 3 * s;
        NCCF_RUN(pA, pW)
    }
    // w[0..11] = X[12s+512 .. 12s+524) (trailing elements).

    // Epilogue: per-lane T_s(512) via neighbor recurrence + shuffle scan.
    //   L_s = sumsq X[12s..12s+12), R_s = sumsq X[12s+512..12s+524)
    //   T_s = T0 + sum_{u<s} (R_u - L_u)
    double Lsum = 0.0, Rsum = 0.0;
    #pragma unroll
    for (int j = 0; j < 12; ++j) {
        Lsum += (double)sq[j];
        Rsum += (double)w[j] * w[j];
    }
    double D = Rsum - Lsum, inc = D;
    #pragma unroll
    for (int off = 1; off < 16; off <<= 1) {
        double v = __shfl_up(inc, off, 16);
        if (s >= off) inc += v;
    }
    const double Ts = T0 + (inc - D);     // T_s(512)

    // Per-lag norms: q(r) = T_s(512+r) - T_s(r).
    double qv[12];
    {
        double Thi = Ts, Tlo = 0.0;
        #pragma unroll
        for (int r = 1; r <= 12; ++r) {
            float eh = w[r - 1];          // X[12s+512+(r-1)]
            Thi += (double)eh * eh;
            Tlo += (double)sq[r - 1];
            qv[r - 1] = Thi - Tlo;
        }
    }

    // Per-lane selection over its 12 lags (fp32, np-like first-max ties).
    float bestv = -1e30f, halfv = -1e30f;
    int bestk = 1 << 30, halfk = 1 << 30;
    {
        float s1 = 1e-9f + sqrtf((float)T0);
        float s1n = s1 * s1;
        #pragma unroll
        for (int r = 1; r <= 12; ++r) {
            int lag  = 12 * s + r;
            int kidx = lag - 1;           // nccf lag index 0..191
            if (kidx <= 188) {
                float s2 = 1e-9f + sqrtf((float)qv[r - 1]);
                float v  = acc[r - 1] / s1n / (s2 * s2);
                if (kidx >= 5) {
                    if (v > bestv) { bestv = v; bestk = kidx; }
                    if (kidx <= 93 && v > halfv) { halfv = v; halfk = kidx; }
                }
            }
        }
    }

    // 16-lane (max, first-argmax) reduction for both slices.
    #pragma unroll
    for (int off = 8; off >= 1; off >>= 1) {
        float ov = __shfl_xor(bestv, off, 16); int ok = __shfl_xor(bestk, off, 16);
        if (ov > bestv || (ov == bestv && ok < bestk)) { bestv = ov; bestk = ok; }
        float hv = __shfl_xor(halfv, off, 16); int hk = __shfl_xor(halfk, off, 16);
        if (hv > halfv || (hv == halfv && hk < halfk)) { halfv = hv; halfk = hk; }
    }

    if (valid && s == 0) {
        bool m = (halfv > 0.99f * bestv);
        int sel = m ? halfk : bestk;
        idxArr[b * NFRM + gf] = sel + 1;  // = chosen lag
    }
}

// ---------------- Kernel 2: 30-wide median filter + pitch ----------------
__global__ __launch_bounds__(256) void med_kernel(const int* __restrict__ idxArr,
                                                  float* __restrict__ out) {
    int gid = blockIdx.x * 256 + threadIdx.x;
    if (gid >= 8 * OUTW) return;
    int b = gid / OUTW;
    int i = gid - b * OUTW;
    float o = 0.0f;
    if (i < MEDLEN) {
        const int* row = idxArr + b * NFRM;
        int vals[WINL];
        #pragma unroll
        for (int m = 0; m < WINL; ++m) {
            int sIdx = i + m - PADL;      // left pad = repeat idx[0]
            vals[m] = row[sIdx < 0 ? 0 : sIdx];
        }
        int med = vals[0];
        #pragma unroll
        for (int c = 0; c < WINL; ++c) {
            int cl = 0, ce = 0;
            #pragma unroll
            for (int m = 0; m < WINL; ++m) {
                cl += (vals[m] <  vals[c]) ? 1 : 0;
                ce += (vals[m] == vals[c]) ? 1 : 0;
            }
            if (cl <= 14 && 14 < cl + ce) med = vals[c];   // rank-14 = sorted[14]
        }
        o = 16000.0f / (1e-9f + (float)med);
    }
    out[gid] = o;
}

extern "C" void kernel_launch(void* const* d_in, const int* in_sizes, int n_in,
                              void* d_out, int out_size, void* d_ws, size_t ws_size,
                              hipStream_t stream) {
    const float* wav = (const float*)d_in[0];
    float* out = (float*)d_out;
    int* idxArr = (int*)d_ws;             // 8*1879 ints = 60128 B

    dim3 gB(NBX, 8);                      // 470 x 8 one-wave blocks, 4 frames each
    hipLaunchKernelGGL(nccf_kernel, gB, dim3(64), 0, stream, wav, idxArr);

    int total = 8 * OUTW;
    hipLaunchKernelGGL(med_kernel, dim3((total + 255) / 256), dim3(256), 0, stream,
                       idxArr, out);
}

// Round 18
// 66.651 us; speedup vs baseline: 1.0048x; 1.0048x over previous
//
#include <hip/hip_runtime.h>

#define T_WPAD  962048   // reflect-padded waveform length (before zero tail)
#define T_RAW   960000
#define NFRM    1879
#define OUTW    1876
#define MEDLEN  1864
#define WINL    30
#define PADL    14
#define FPB     4        // frames per block
#define NBX     470      // ceil(NFRM / FPB)
#define XLEN    2244     // 3*512 + 705 + pad (float4-divisible)
#define X4LEN   561

// Rotated inner body: window offset O (0/4/8/12), all indices compile-time.
// Reads w[(O+1)..(O+15) mod 16]; loads content k+4 into the retiring slots
// w[O..O+3]; loads A(k+1). PA/PW select the source; with PA=global and
// PW=LDS the two loads sit on DIFFERENT pipes (vmcnt vs lgkmcnt).
// 2 loads + 48 fmaf, nothing else.
#define NCCF_BODY(O, AUSE, ALOAD, K, PA, PW)                                    \
    {                                                                           \
        ALOAD = PA[(K) + 1];                                                    \
        float4 nx = PW[(K) + 4];                                                \
        _Pragma("unroll")                                                       \
        for (int r = 0; r < 12; ++r) {                                          \
            acc[r] = fmaf(AUSE.x, w[(O + r + 1) & 15], acc[r]);                 \
            acc[r] = fmaf(AUSE.y, w[(O + r + 2) & 15], acc[r]);                 \
            acc[r] = fmaf(AUSE.z, w[(O + r + 3) & 15], acc[r]);                 \
            acc[r] = fmaf(AUSE.w, w[(O + r + 4) & 15], acc[r]);                 \
        }                                                                       \
        w[(O + 0) & 15] = nx.x; w[(O + 1) & 15] = nx.y;                         \
        w[(O + 2) & 15] = nx.z; w[(O + 3) & 15] = nx.w;                         \
    }

// Prologue + main loop over a given pair of base pointers.
#define NCCF_RUN(PA, PW)                                                        \
    {                                                                           \
        const float4* fb = (PA) + 8 * s;                                        \
        _Pragma("unroll")                                                       \
        for (int m = 0; m < 8; ++m) {                                           \
            float4 v4 = fb[m];                                                  \
            T0 += (double)v4.x * v4.x; T0 += (double)v4.y * v4.y;               \
            T0 += (double)v4.z * v4.z; T0 += (double)v4.w * v4.w;               \
        }                                                                       \
        _Pragma("unroll")                                                       \
        for (int off = 8; off >= 1; off >>= 1) T0 += __shfl_xor(T0, off, 16);   \
        _Pragma("unroll")                                                       \
        for (int d = 0; d < 4; ++d) {                                           \
            float4 t4 = (PW)[d];                                                \
            w[4*d] = t4.x; w[4*d+1] = t4.y; w[4*d+2] = t4.z; w[4*d+3] = t4.w;   \
        }                                                                       \
        _Pragma("unroll")                                                       \
        for (int j = 0; j < 12; ++j) sq[j] = w[j] * w[j];                       \
        Aev = (PA)[0];                                                          \
        _Pragma("unroll 2")                                                     \
        for (int kg = 0; kg < 32; ++kg) {                                       \
            const int k4 = kg * 4;                                              \
            NCCF_BODY(0,  Aev, Aod, k4 + 0, (PA), (PW))                         \
            NCCF_BODY(4,  Aod, Aev, k4 + 1, (PA), (PW))                         \
            NCCF_BODY(8,  Aev, Aod, k4 + 2, (PA), (PW))                         \
            NCCF_BODY(12, Aod, Aev, k4 + 3, (PA), (PW))                         \
        }                                                                       \
    }

// ---------------- Kernel 1: NCCF + per-frame lag selection ----------------
// 64 thr = 1 wave per block; wave handles FOUR frames (one per 16-lane group).
// g = lane>>4 picks frame, s = lane&15 owns lags 12s+1..12s+12.
// HYBRID pipe split (R16 + A-stream on VMEM): window stream stays in LDS
// (native b128 pattern, halved LDS-pipe demand); A-stream reads straight
// from global for interior blocks (4 distinct 16B addrs/wave, L1-resident,
// waits on vmcnt not lgkmcnt -> no cross-pipe serialization). Boundary
// blocks (16/3760) use the all-LDS R16 path verbatim.
// Norms: cooperative f64 frame norm T0 + neighbor-recurrence shuffle scan.
__global__ __launch_bounds__(64) void nccf_kernel(const float* __restrict__ wav,
                                                  int* __restrict__ idxArr) {
    const int bx   = blockIdx.x;
    const int b    = blockIdx.y;
    const int tid  = threadIdx.x;
    const int lane = tid & 63;
    const int g    = lane >> 4;          // frame within block (0..3)
    const int s    = lane & 15;          // lag-group lane (0..15)

    __shared__ __align__(16) float X[XLEN];

    const long a0 = (long)bx * (FPB * 512);
    const float* wrow = wav + (long)b * T_RAW;
    const bool interior = (bx >= 1 && bx <= NBX - 2);

    // Stage wp[a0 .. a0+XLEN): vectorized fast path for interior blocks.
    if (interior) {
        const float4* src = (const float4*)(wrow + (a0 - 1024));
        float4* dst = (float4*)X;
        for (int i = tid; i < X4LEN; i += 64) dst[i] = src[i];
    } else {
        for (int i = tid; i < XLEN; i += 64) {
            float v = 0.0f;
            long t = a0 + i;
            if (t < T_WPAD) {
                long u = t - 1024;
                if (u < 0) u = -u;
                if (u >= T_RAW) u = 2L * (T_RAW - 1) - u;
                v = wrow[u];
            }
            X[i] = v;
        }
    }
    __syncthreads();

    const int F  = g;                    // frame within block
    const int gf = bx * FPB + F;         // global frame
    const bool valid = (gf < NFRM);

    double T0 = 0.0;
    float acc[12];
    #pragma unroll
    for (int r = 0; r < 12; ++r) acc[r] = 0.0f;
    float sq[12];                        // X[12s+j]^2, j=0..11
    float w[16];
    float4 Aev, Aod;

    const float4* X4 = (const float4*)X;
    const float4* pW = X4 + F * 128 + 3 * s;   // lane window base (LDS)

    if (interior) {
        // wp[a0 + e] == wav[b*T_RAW + a0 - 1024 + e] for all tile elements.
        const float4* G4 = (const float4*)(wrow + (a0 - 1024));
        const float4* pA = G4 + F * 128;       // frame base (GLOBAL)
        NCCF_RUN(pA, pW)
    } else {
        const float4* pA = X4 + F * 128;       // frame base (LDS)
        NCCF_RUN(pA, pW)
    }
    // w[0..11] = X[12s+512 .. 12s+524) (trailing elements).

    // Epilogue: per-lane T_s(512) via neighbor recurrence + shuffle scan.
    //   L_s = sumsq X[12s..12s+12), R_s = sumsq X[12s+512..12s+524)
    //   T_s = T0 + sum_{u<s} (R_u - L_u)
    double Lsum = 0.0, Rsum = 0.0;
    #pragma unroll
    for (int j = 0; j < 12; ++j) {
        Lsum += (double)sq[j];
        Rsum += (double)w[j] * w[j];
    }
    double D = Rsum - Lsum, inc = D;
    #pragma unroll
    for (int off = 1; off < 16; off <<= 1) {
        double v = __shfl_up(inc, off, 16);
        if (s >= off) inc += v;
    }
    const double Ts = T0 + (inc - D);     // T_s(512)

    // Per-lag norms: q(r) = T_s(512+r) - T_s(r).
    double qv[12];
    {
        double Thi = Ts, Tlo = 0.0;
        #pragma unroll
        for (int r = 1; r <= 12; ++r) {
            float eh = w[r - 1];          // X[12s+512+(r-1)]
            Thi += (double)eh * eh;
            Tlo += (double)sq[r - 1];
            qv[r - 1] = Thi - Tlo;
        }
    }

    // Per-lane selection over its 12 lags (fp32, np-like first-max ties).
    float bestv = -1e30f, halfv = -1e30f;
    int bestk = 1 << 30, halfk = 1 << 30;
    {
        float s1 = 1e-9f + sqrtf((float)T0);
        float s1n = s1 * s1;
        #pragma unroll
        for (int r = 1; r <= 12; ++r) {
            int lag  = 12 * s + r;
            int kidx = lag - 1;           // nccf lag index 0..191
            if (kidx <= 188) {
                float s2 = 1e-9f + sqrtf((float)qv[r - 1]);
                float v  = acc[r - 1] / s1n / (s2 * s2);
                if (kidx >= 5) {
                    if (v > bestv) { bestv = v; bestk = kidx; }
                    if (kidx <= 93 && v > halfv) { halfv = v; halfk = kidx; }
                }
            }
        }
    }

    // 16-lane (max, first-argmax) reduction for both slices.
    #pragma unroll
    for (int off = 8; off >= 1; off >>= 1) {
        float ov = __shfl_xor(bestv, off, 16); int ok = __shfl_xor(bestk, off, 16);
        if (ov > bestv || (ov == bestv && ok < bestk)) { bestv = ov; bestk = ok; }
        float hv = __shfl_xor(halfv, off, 16); int hk = __shfl_xor(halfk, off, 16);
        if (hv > halfv || (hv == halfv && hk < halfk)) { halfv = hv; halfk = hk; }
    }

    if (valid && s == 0) {
        bool m = (halfv > 0.99f * bestv);
        int sel = m ? halfk : bestk;
        idxArr[b * NFRM + gf] = sel + 1;  // = chosen lag
    }
}

// ---------------- Kernel 2: 30-wide median filter + pitch ----------------
__global__ __launch_bounds__(256) void med_kernel(const int* __restrict__ idxArr,
                                                  float* __restrict__ out) {
    int gid = blockIdx.x * 256 + threadIdx.x;
    if (gid >= 8 * OUTW) return;
    int b = gid / OUTW;
    int i = gid - b * OUTW;
    float o = 0.0f;
    if (i < MEDLEN) {
        const int* row = idxArr + b * NFRM;
        int vals[WINL];
        #pragma unroll
        for (int m = 0; m < WINL; ++m) {
            int sIdx = i + m - PADL;      // left pad = repeat idx[0]
            vals[m] = row[sIdx < 0 ? 0 : sIdx];
        }
        int med = vals[0];
        #pragma unroll
        for (int c = 0; c < WINL; ++c) {
            int cl = 0, ce = 0;
            #pragma unroll
            for (int m = 0; m < WINL; ++m) {
                cl += (vals[m] <  vals[c]) ? 1 : 0;
                ce += (vals[m] == vals[c]) ? 1 : 0;
            }
            if (cl <= 14 && 14 < cl + ce) med = vals[c];   // rank-14 = sorted[14]
        }
        o = 16000.0f / (1e-9f + (float)med);
    }
    out[gid] = o;
}

extern "C" void kernel_launch(void* const* d_in, const int* in_sizes, int n_in,
                              void* d_out, int out_size, void* d_ws, size_t ws_size,
                              hipStream_t stream) {
    const float* wav = (const float*)d_in[0];
    float* out = (float*)d_out;
    int* idxArr = (int*)d_ws;             // 8*1879 ints = 60128 B

    dim3 gB(NBX, 8);                      // 470 x 8 one-wave blocks, 4 frames each
    hipLaunchKernelGGL(nccf_kernel, gB, dim3(64), 0, stream, wav, idxArr);

    int total = 8 * OUTW;
    hipLaunchKernelGGL(med_kernel, dim3((total + 255) / 256), dim3(256), 0, stream,
                       idxArr, out);
}

// Round 19
// 61.214 us; speedup vs baseline: 1.0941x; 1.0888x over previous
//
#include <hip/hip_runtime.h>

#define T_WPAD  962048   // reflect-padded waveform length (before zero tail)
#define T_RAW   960000
#define NFRM    1879
#define OUTW    1876
#define MEDLEN  1864
#define WINL    30
#define PADL    14
#define FPB     4        // frames per block
#define NBX     470      // ceil(NFRM / FPB)
#define XLEN    2244     // 3*512 + 705 + pad (float4-divisible)
#define X4LEN   561

// Rotated inner body: window offset O (0/4/8/12), all indices compile-time.
// Reads w[(O+1)..(O+15) mod 16]; loads window content k+4 into the retiring
// slots w[O..O+3]; loads A content k+2 into the A-register that body k+2
// will consume (period-4 rotation -> dependency distance 2 bodies ~200cy,
// above ds_read latency). 2 ds_read_b128 + 48 fmaf, nothing else.
#define NCCF_BODY(O, AUSE, ALOAD, K, PA, PW)                                    \
    {                                                                           \
        ALOAD = PA[(K) + 2];                                                    \
        float4 nx = PW[(K) + 4];                                                \
        _Pragma("unroll")                                                       \
        for (int r = 0; r < 12; ++r) {                                          \
            acc[r] = fmaf(AUSE.x, w[(O + r + 1) & 15], acc[r]);                 \
            acc[r] = fmaf(AUSE.y, w[(O + r + 2) & 15], acc[r]);                 \
            acc[r] = fmaf(AUSE.z, w[(O + r + 3) & 15], acc[r]);                 \
            acc[r] = fmaf(AUSE.w, w[(O + r + 4) & 15], acc[r]);                 \
        }                                                                       \
        w[(O + 0) & 15] = nx.x; w[(O + 1) & 15] = nx.y;                         \
        w[(O + 2) & 15] = nx.z; w[(O + 3) & 15] = nx.w;                         \
    }

// Prologue + main loop over a given pair of base pointers.
#define NCCF_RUN(PA, PW)                                                        \
    {                                                                           \
        const float4* fb = (PA) + 8 * s;                                        \
        _Pragma("unroll")                                                       \
        for (int m = 0; m < 8; ++m) {                                           \
            float4 v4 = fb[m];                                                  \
            T0 += (double)v4.x * v4.x; T0 += (double)v4.y * v4.y;               \
            T0 += (double)v4.z * v4.z; T0 += (double)v4.w * v4.w;               \
        }                                                                       \
        _Pragma("unroll")                                                       \
        for (int off = 8; off >= 1; off >>= 1) T0 += __shfl_xor(T0, off, 16);   \
        _Pragma("unroll")                                                       \
        for (int d = 0; d < 4; ++d) {                                           \
            float4 t4 = (PW)[d];                                                \
            w[4*d] = t4.x; w[4*d+1] = t4.y; w[4*d+2] = t4.z; w[4*d+3] = t4.w;   \
        }                                                                       \
        _Pragma("unroll")                                                       \
        for (int j = 0; j < 12; ++j) sq[j] = w[j] * w[j];                       \
        A0 = (PA)[0]; A1 = (PA)[1];                                             \
        _Pragma("unroll 2")                                                     \
        for (int kg = 0; kg < 32; ++kg) {                                       \
            const int k4 = kg * 4;                                              \
            NCCF_BODY(0,  A0, A2, k4 + 0, (PA), (PW))                           \
            NCCF_BODY(4,  A1, A3, k4 + 1, (PA), (PW))                           \
            NCCF_BODY(8,  A2, A0, k4 + 2, (PA), (PW))                           \
            NCCF_BODY(12, A3, A1, k4 + 3, (PA), (PW))                           \
        }                                                                       \
    }

// ---------------- Kernel 1: NCCF + per-frame lag selection ----------------
// 64 thr = 1 wave per block; wave handles FOUR frames (one per 16-lane group).
// g = lane>>4 picks frame, s = lane&15 owns lags 12s+1..12s+12.
// R16 structure (all-LDS, minimal body) + A-stream lookahead-2.
// Norms: cooperative f64 frame norm T0 + neighbor-recurrence shuffle scan.
__global__ __launch_bounds__(64) void nccf_kernel(const float* __restrict__ wav,
                                                  int* __restrict__ idxArr) {
    const int bx   = blockIdx.x;
    const int b    = blockIdx.y;
    const int tid  = threadIdx.x;
    const int lane = tid & 63;
    const int g    = lane >> 4;          // frame within block (0..3)
    const int s    = lane & 15;          // lag-group lane (0..15)

    __shared__ __align__(16) float X[XLEN];

    const long a0 = (long)bx * (FPB * 512);
    const float* wrow = wav + (long)b * T_RAW;
    const bool interior = (bx >= 1 && bx <= NBX - 2);

    // Stage wp[a0 .. a0+XLEN): vectorized fast path for interior blocks.
    if (interior) {
        const float4* src = (const float4*)(wrow + (a0 - 1024));
        float4* dst = (float4*)X;
        for (int i = tid; i < X4LEN; i += 64) dst[i] = src[i];
    } else {
        for (int i = tid; i < XLEN; i += 64) {
            float v = 0.0f;
            long t = a0 + i;
            if (t < T_WPAD) {
                long u = t - 1024;
                if (u < 0) u = -u;
                if (u >= T_RAW) u = 2L * (T_RAW - 1) - u;
                v = wrow[u];
            }
            X[i] = v;
        }
    }
    __syncthreads();

    const int F  = g;                    // frame within block
    const int gf = bx * FPB + F;         // global frame
    const bool valid = (gf < NFRM);

    double T0 = 0.0;
    float acc[12];
    #pragma unroll
    for (int r = 0; r < 12; ++r) acc[r] = 0.0f;
    float sq[12];                        // X[12s+j]^2, j=0..11
    float w[16];
    float4 A0, A1, A2, A3;

    const float4* X4 = (const float4*)X;
    const float4* pA = X4 + F * 128;     // frame base (float4)
    const float4* pW = pA + 3 * s;       // lane window base (float4)
    NCCF_RUN(pA, pW)
    // w[0..11] = X[12s+512 .. 12s+524) (trailing elements).

    // Epilogue: per-lane T_s(512) via neighbor recurrence + shuffle scan.
    //   L_s = sumsq X[12s..12s+12), R_s = sumsq X[12s+512..12s+524)
    //   T_s = T0 + sum_{u<s} (R_u - L_u)
    double Lsum = 0.0, Rsum = 0.0;
    #pragma unroll
    for (int j = 0; j < 12; ++j) {
        Lsum += (double)sq[j];
        Rsum += (double)w[j] * w[j];
    }
    double D = Rsum - Lsum, inc = D;
    #pragma unroll
    for (int off = 1; off < 16; off <<= 1) {
        double v = __shfl_up(inc, off, 16);
        if (s >= off) inc += v;
    }
    const double Ts = T0 + (inc - D);     // T_s(512)

    // Per-lag norms: q(r) = T_s(512+r) - T_s(r).
    double qv[12];
    {
        double Thi = Ts, Tlo = 0.0;
        #pragma unroll
        for (int r = 1; r <= 12; ++r) {
            float eh = w[r - 1];          // X[12s+512+(r-1)]
            Thi += (double)eh * eh;
            Tlo += (double)sq[r - 1];
            qv[r - 1] = Thi - Tlo;
        }
    }

    // Per-lane selection over its 12 lags (fp32, np-like first-max ties).
    float bestv = -1e30f, halfv = -1e30f;
    int bestk = 1 << 30, halfk = 1 << 30;
    {
        float s1 = 1e-9f + sqrtf((float)T0);
        float s1n = s1 * s1;
        #pragma unroll
        for (int r = 1; r <= 12; ++r) {
            int lag  = 12 * s + r;
            int kidx = lag - 1;           // nccf lag index 0..191
            if (kidx <= 188) {
                float s2 = 1e-9f + sqrtf((float)qv[r - 1]);
                float v  = acc[r - 1] / s1n / (s2 * s2);
                if (kidx >= 5) {
                    if (v > bestv) { bestv = v; bestk = kidx; }
                    if (kidx <= 93 && v > halfv) { halfv = v; halfk = kidx; }
                }
            }
        }
    }

    // 16-lane (max, first-argmax) reduction for both slices.
    #pragma unroll
    for (int off = 8; off >= 1; off >>= 1) {
        float ov = __shfl_xor(bestv, off, 16); int ok = __shfl_xor(bestk, off, 16);
        if (ov > bestv || (ov == bestv && ok < bestk)) { bestv = ov; bestk = ok; }
        float hv = __shfl_xor(halfv, off, 16); int hk = __shfl_xor(halfk, off, 16);
        if (hv > halfv || (hv == halfv && hk < halfk)) { halfv = hv; halfk = hk; }
    }

    if (valid && s == 0) {
        bool m = (halfv > 0.99f * bestv);
        int sel = m ? halfk : bestk;
        idxArr[b * NFRM + gf] = sel + 1;  // = chosen lag
    }
}

// ---------------- Kernel 2: 30-wide median filter + pitch ----------------
__global__ __launch_bounds__(256) void med_kernel(const int* __restrict__ idxArr,
                                                  float* __restrict__ out) {
    int gid = blockIdx.x * 256 + threadIdx.x;
    if (gid >= 8 * OUTW) return;
    int b = gid / OUTW;
    int i = gid - b * OUTW;
    float o = 0.0f;
    if (i < MEDLEN) {
        const int* row = idxArr + b * NFRM;
        int vals[WINL];
        #pragma unroll
        for (int m = 0; m < WINL; ++m) {
            int sIdx = i + m - PADL;      // left pad = repeat idx[0]
            vals[m] = row[sIdx < 0 ? 0 : sIdx];
        }
        int med = vals[0];
        #pragma unroll
        for (int c = 0; c < WINL; ++c) {
            int cl = 0, ce = 0;
            #pragma unroll
            for (int m = 0; m < WINL; ++m) {
                cl += (vals[m] <  vals[c]) ? 1 : 0;
                ce += (vals[m] == vals[c]) ? 1 : 0;
            }
            if (cl <= 14 && 14 < cl + ce) med = vals[c];   // rank-14 = sorted[14]
        }
        o = 16000.0f / (1e-9f + (float)med);
    }
    out[gid] = o;
}

extern "C" void kernel_launch(void* const* d_in, const int* in_sizes, int n_in,
                              void* d_out, int out_size, void* d_ws, size_t ws_size,
                              hipStream_t stream) {
    const float* wav = (const float*)d_in[0];
    float* out = (float*)d_out;
    int* idxArr = (int*)d_ws;             // 8*1879 ints = 60128 B

    dim3 gB(NBX, 8);                      // 470 x 8 one-wave blocks, 4 frames each
    hipLaunchKernelGGL(nccf_kernel, gB, dim3(64), 0, stream, wav, idxArr);

    int total = 8 * OUTW;
    hipLaunchKernelGGL(med_kernel, dim3((total + 255) / 256), dim3(256), 0, stream,
                       idxArr, out);
}